// Round 4
// baseline (195.898 us; speedup 1.0000x reference)
//
#include <hip/hip_runtime.h>
#include <hip/hip_bf16.h>

// Attention head: context/softmax over (B=32, S=2048, DEC=512, ENC2=1024)
// d_in[0] = s        (1,32,512)   f32
// d_in[1] = enc      (32,2048,1024) f32
// d_in[2] = W_attn   (512,1536)   f32   [:, :512]=W_s  [:,512:]=W_e
// d_in[3] = W_v      (1,512)      f32
// d_out   = context (32,1024) f32  ++  soft (32,2048) f32

typedef __attribute__((ext_vector_type(8))) short bf16x8;
typedef __attribute__((ext_vector_type(4))) float f32x4;
typedef __attribute__((address_space(3))) unsigned lds_u32;
typedef const __attribute__((address_space(1))) unsigned g_u32;

#define SB0() __builtin_amdgcn_sched_barrier(0)

static __device__ __forceinline__ unsigned short f2bf(float f) {
    union { float f; unsigned u; } v; v.f = f;
    unsigned r = (v.u + 0x7fffu + ((v.u >> 16) & 1u)) >> 16;  // RNE
    return (unsigned short)r;
}

static __device__ __forceinline__ unsigned pk2(float x, float y) {
    union { __hip_bfloat162 h; unsigned u; } c;
    c.h = __float22bfloat162_rn(make_float2(x, y));  // v_cvt_pk_bf16_f32
    return c.u;
}

static __device__ __forceinline__ float fast_tanh(float x) {
    return 1.0f - 2.0f / (__expf(2.0f * x) + 1.0f);
}

// ---------------- prep: sW[b,h] = sum_d s[b,d] * W_attn[h, d] ----------------
__global__ __launch_bounds__(256) void prep_sw(const float* __restrict__ s,
                                               const float* __restrict__ Wat,
                                               float* __restrict__ sW) {
    int id = blockIdx.x * 256 + threadIdx.x;   // 16384 = 32b * 512h
    int b = id >> 9, h = id & 511;
    const float4* wr = (const float4*)(Wat + (size_t)h * 1536);
    const float4* sr = (const float4*)(s + (size_t)b * 512);
    float acc = 0.f;
#pragma unroll 8
    for (int i = 0; i < 128; ++i) {
        float4 w = wr[i], sv = sr[i];
        acc += w.x * sv.x + w.y * sv.y + w.z * sv.z + w.w * sv.w;
    }
    sW[id] = acc;
}

// ------- prep: WebfB fragment-major bf16 repack of W_e = W_attn[:,512:] -----
// Layout: [cg(8)][step(16)][kk(2)][nf(4)][lane(64)][j(8)]
// element = W_e[col = cg*64+nf*16+(lane&15)][k = step*64+kk*32+(lane>>4)*8+j]
__global__ __launch_bounds__(256) void prep_weB(const float* __restrict__ Wat,
                                                unsigned short* __restrict__ WebfB) {
    int tid = blockIdx.x * 256 + threadIdx.x;  // 0..65535
    int lane = tid & 63;
    int g = tid >> 6;
    int nf = g & 3, kk = (g >> 2) & 1, i = (g >> 3) & 15, w = g >> 7;
    int col = w * 64 + nf * 16 + (lane & 15);
    int k0 = i * 64 + kk * 32 + (lane >> 4) * 8;
    const float* src = Wat + (size_t)col * 1536 + 512 + k0;
    float4 w0 = *(const float4*)src;
    float4 w1 = *(const float4*)(src + 4);
    union { unsigned short us[8]; int4 v; } p;
    p.us[0] = f2bf(w0.x); p.us[1] = f2bf(w0.y); p.us[2] = f2bf(w0.z); p.us[3] = f2bf(w0.w);
    p.us[4] = f2bf(w1.x); p.us[5] = f2bf(w1.y); p.us[6] = f2bf(w1.z); p.us[7] = f2bf(w1.w);
    *(int4*)(WebfB + (size_t)tid * 8) = p.v;
}

// ---------------- energy+atten: atten[m] = sum_h tanh(sW+enc.W_e^T)*Wv[h] ----
// Block: 64 rows x 256 cols, 4 waves x 64 cols. Grid 2048 (N split in 2).
// K-step 64, 3 LDS A-buffers, counted-vmcnt pipeline (raw s_barrier, never
// drain to 0 in the loop). Issue order: B(i+1) regs BEFORE A(i+2) gload_lds
// so B-waits never transitively wait on HBM.
__global__ __launch_bounds__(256, 2) void energy_kernel(
    const float* __restrict__ enc, const unsigned short* __restrict__ WebfB,
    const float* __restrict__ sW, const float* __restrict__ Wv,
    float* __restrict__ atten) {
    __shared__ __align__(16) float lA[3][4096];  // 3 x 16 KiB A-tiles
    __shared__ float lred[4][64];

    const int t = threadIdx.x;       // 0..255
    const int lane = t & 63;
    const int wave = t >> 6;
    const int bid = blockIdx.x;
    const int m0 = (bid & 1023) * 64;     // pair (j, j+1024) shares A-tile, same XCD
    const int nh = bid >> 10;
    const int b = m0 >> 11;
    const int l15 = lane & 15;
    const int lkg = lane >> 4;            // k-group 0..3
    const int cg = nh * 4 + wave;         // col group 0..7
    const int n0 = cg * 64;

    // A staging: 4 gload_lds per thread per step; gload q covers rows
    // wave*16+q*4 .. +3. lane lands at row rq = wave*16+q*4+(lane>>4),
    // LDS chunk l15; inverse-swizzled global source chunk = l15 ^ (rq&7).
    const float* gsrc[4];
    int ldoff[4];
#pragma unroll
    for (int q = 0; q < 4; ++q) {
        int rq = wave * 16 + q * 4 + lkg;
        int cl = l15 ^ (rq & 7);
        gsrc[q] = enc + (size_t)(m0 + rq) * 1024 + cl * 4;
        ldoff[q] = (wave * 16 + q * 4) * 64;
    }

    const unsigned short* wB = WebfB + (size_t)cg * 65536 + lane * 8;

    f32x4 acc[4][4];
#pragma unroll
    for (int mf = 0; mf < 4; ++mf)
#pragma unroll
        for (int nf = 0; nf < 4; ++nf) acc[mf][nf] = (f32x4){0.f, 0.f, 0.f, 0.f};

    auto stage = [&](int step, float* buf) {
#pragma unroll
        for (int q = 0; q < 4; ++q)
            __builtin_amdgcn_global_load_lds((g_u32*)(gsrc[q] + step * 64),
                                             (lds_u32*)(buf + ldoff[q]), 16, 0, 0);
    };
    auto loadB = [&](int step, bf16x8* bf) {
#pragma unroll
        for (int kk = 0; kk < 2; ++kk)
#pragma unroll
            for (int nf = 0; nf < 4; ++nf)
                bf[kk * 4 + nf] = *(const bf16x8*)(wB + (((step * 2 + kk) * 4 + nf) << 9));
    };
    auto compute = [&](const float* lbuf, const bf16x8* bf) {
#pragma unroll
        for (int kk = 0; kk < 2; ++kk) {
            const int c0 = kk * 8 + lkg * 2;
#pragma unroll
            for (int mf = 0; mf < 4; ++mf) {
                const int r = mf * 16 + l15;
                const int r7 = r & 7;
                float4 a0 = *(const float4*)&lbuf[r * 64 + ((c0 ^ r7) << 2)];
                float4 a1 = *(const float4*)&lbuf[r * 64 + (((c0 + 1) ^ r7) << 2)];
                union { unsigned u[4]; bf16x8 v; } af;
                af.u[0] = pk2(a0.x, a0.y); af.u[1] = pk2(a0.z, a0.w);
                af.u[2] = pk2(a1.x, a1.y); af.u[3] = pk2(a1.z, a1.w);
#pragma unroll
                for (int nf = 0; nf < 4; ++nf)
                    acc[mf][nf] = __builtin_amdgcn_mfma_f32_16x16x32_bf16(
                        af.v, bf[kk * 4 + nf], acc[mf][nf], 0, 0, 0);
            }
        }
    };

    float* p0 = (float*)lA[0];
    float* p1 = (float*)lA[1];
    float* p2 = (float*)lA[2];
    bf16x8 bA[8], bB[8];

    // prologue: stream order A(0), B(0), A(1)  -> 16 vmem ops in flight
    stage(0, p0);
    loadB(0, bA);
    stage(1, p1);

#pragma unroll 1
    for (int k = 0; k < 7; ++k) {
        const int i = 2 * k;
        // even step i: uses bA
        asm volatile("s_waitcnt vmcnt(12)" ::: "memory");  // A(i) retired
        SB0();
        __builtin_amdgcn_s_barrier();                      // tile visible
        loadB(i + 1, bB);                                  // B before younger A
        SB0();
        stage(i + 2, p2);
        SB0();
        compute(p0, bA);
        { float* tp = p0; p0 = p1; p1 = p2; p2 = tp; }
        // odd step i+1: uses bB
        asm volatile("s_waitcnt vmcnt(12)" ::: "memory");
        SB0();
        __builtin_amdgcn_s_barrier();
        loadB(i + 2, bA);
        SB0();
        stage(i + 3, p2);
        SB0();
        compute(p0, bB);
        { float* tp = p0; p0 = p1; p1 = p2; p2 = tp; }
    }
    // step 14 (uses bA): no more A staging
    asm volatile("s_waitcnt vmcnt(12)" ::: "memory");
    SB0();
    __builtin_amdgcn_s_barrier();
    loadB(15, bB);
    SB0();
    compute(p0, bA);
    { float* tp = p0; p0 = p1; p1 = p2; p2 = tp; }
    // step 15 (uses bB): outstanding = A(15)[4] + B(15)[8] -> wait A(15)
    asm volatile("s_waitcnt vmcnt(8)" ::: "memory");
    SB0();
    __builtin_amdgcn_s_barrier();
    compute(p0, bB);

    // epilogue: tanh + dot with Wv over this wave's 64 cols
    float sWv[4], wvv[4];
#pragma unroll
    for (int nf = 0; nf < 4; ++nf) {
        int col = n0 + nf * 16 + l15;
        sWv[nf] = sW[(b << 9) + col];
        wvv[nf] = Wv[col];
    }
    float pa[4][4];
#pragma unroll
    for (int mf = 0; mf < 4; ++mf) {
#pragma unroll
        for (int r = 0; r < 4; ++r) pa[mf][r] = 0.f;
#pragma unroll
        for (int nf = 0; nf < 4; ++nf)
#pragma unroll
            for (int r = 0; r < 4; ++r)
                pa[mf][r] += fast_tanh(acc[mf][nf][r] + sWv[nf]) * wvv[nf];
    }
#pragma unroll
    for (int m = 1; m < 16; m <<= 1)
#pragma unroll
        for (int mf = 0; mf < 4; ++mf)
#pragma unroll
            for (int r = 0; r < 4; ++r)
                pa[mf][r] += __shfl_xor(pa[mf][r], m, 64);

    if (l15 == 0) {
#pragma unroll
        for (int mf = 0; mf < 4; ++mf)
#pragma unroll
            for (int r = 0; r < 4; ++r)
                lred[wave][mf * 16 + lkg * 4 + r] = pa[mf][r];
    }
    __syncthreads();
    if (t < 64) {
        float ssum = lred[0][t] + lred[1][t] + lred[2][t] + lred[3][t];
        // two N-half blocks contribute: atten laid out [nh][32768]? no --
        // each (m-row) needs sum over all 512 cols = both halves.
        atomicAdd(&atten[m0 + t], ssum);
    }
}

// zero atten before energy (atomicAdd accumulation target)
__global__ __launch_bounds__(256) void zero_atten(float* __restrict__ atten) {
    atten[blockIdx.x * 256 + threadIdx.x] = 0.f;
}

// ---------------- softmax over S=2048 per batch row ----------------
__global__ __launch_bounds__(256) void softmax_kernel(const float* __restrict__ atten,
                                                      float* __restrict__ out) {
    int b = blockIdx.x, t = threadIdx.x;
    const float* row = atten + b * 2048;
    float v[8];
#pragma unroll
    for (int i = 0; i < 8; ++i) v[i] = row[t + 256 * i];
    float mx = v[0];
#pragma unroll
    for (int i = 1; i < 8; ++i) mx = fmaxf(mx, v[i]);
#pragma unroll
    for (int m = 1; m < 64; m <<= 1) mx = fmaxf(mx, __shfl_xor(mx, m, 64));
    __shared__ float redm[4], reds[4];
    if ((t & 63) == 0) redm[t >> 6] = mx;
    __syncthreads();
    mx = fmaxf(fmaxf(redm[0], redm[1]), fmaxf(redm[2], redm[3]));
    float sum = 0.f;
#pragma unroll
    for (int i = 0; i < 8; ++i) { v[i] = __expf(v[i] - mx); sum += v[i]; }
#pragma unroll
    for (int m = 1; m < 64; m <<= 1) sum += __shfl_xor(sum, m, 64);
    if ((t & 63) == 0) reds[t >> 6] = sum;
    __syncthreads();
    sum = reds[0] + reds[1] + reds[2] + reds[3];
    float inv = 1.0f / sum;
    float* soft = out + 32768;
#pragma unroll
    for (int i = 0; i < 8; ++i) soft[b * 2048 + t + 256 * i] = v[i] * inv;
}

// ---------------- context partial: 32 chunks of 64 rows per batch ----------
__global__ __launch_bounds__(256) void ctx_partial(const float* __restrict__ enc,
                                                   const float* __restrict__ soft,
                                                   float* __restrict__ part) {
    int blk = blockIdx.x;               // b*32 + chunk
    int b = blk >> 5, s0 = (blk & 31) * 64;
    int t = threadIdx.x;
    float4 a = {0.f, 0.f, 0.f, 0.f};
    const float* base = enc + ((size_t)(b * 2048 + s0)) * 1024 + t * 4;
    const float* sw = soft + b * 2048 + s0;
#pragma unroll 4
    for (int s = 0; s < 64; ++s) {
        float w = sw[s];
        float4 e = *(const float4*)(base + (size_t)s * 1024);
        a.x += w * e.x; a.y += w * e.y; a.z += w * e.z; a.w += w * e.w;
    }
    *(float4*)(part + (size_t)blk * 1024 + t * 4) = a;
}

__global__ __launch_bounds__(256) void ctx_reduce(const float* __restrict__ part,
                                                  float* __restrict__ ctx) {
    int id = blockIdx.x * 256 + threadIdx.x;  // 32768 = 32b * 1024e
    int b = id >> 10, e = id & 1023;
    float s = 0.f;
#pragma unroll 8
    for (int c = 0; c < 32; ++c) s += part[((size_t)(b * 32 + c)) * 1024 + e];
    ctx[id] = s;
}

extern "C" void kernel_launch(void* const* d_in, const int* in_sizes, int n_in,
                              void* d_out, int out_size, void* d_ws, size_t ws_size,
                              hipStream_t stream) {
    const float* s   = (const float*)d_in[0];
    const float* enc = (const float*)d_in[1];
    const float* Wat = (const float*)d_in[2];
    const float* Wv  = (const float*)d_in[3];
    float* out = (float*)d_out;

    char* ws = (char*)d_ws;
    float* sW             = (float*)ws;                                   // 64 KiB
    unsigned short* WebfB = (unsigned short*)(ws + (64 << 10));           // 1 MiB
    float* atten          = (float*)(ws + (64 << 10) + (1 << 20));        // 256 KiB
    float* part           = (float*)(ws + (64 << 10) + (1 << 20) + (256 << 10)); // 4 MiB

    prep_sw<<<64, 256, 0, stream>>>(s, Wat, sW);
    prep_weB<<<256, 256, 0, stream>>>(Wat, WebfB);
    zero_atten<<<256, 256, 0, stream>>>(atten);
    energy_kernel<<<2048, 256, 0, stream>>>(enc, WebfB, sW, Wv, atten);
    softmax_kernel<<<32, 256, 0, stream>>>(atten, out);
    ctx_partial<<<1024, 256, 0, stream>>>(enc, out + 32768, part);
    ctx_reduce<<<128, 256, 0, stream>>>(part, out);
}

// Round 5
// 180.226 us; speedup vs baseline: 1.0870x; 1.0870x over previous
//
#include <hip/hip_runtime.h>
#include <hip/hip_bf16.h>

// Attention head: context/softmax over (B=32, S=2048, DEC=512, ENC2=1024)
// d_in[0] = s (1,32,512) f32 | d_in[1] = enc (32,2048,1024) f32
// d_in[2] = W_attn (512,1536) f32 | d_in[3] = W_v (1,512) f32
// d_out = context (32,1024) f32 ++ soft (32,2048) f32

typedef __attribute__((ext_vector_type(8))) short bf16x8;
typedef __attribute__((ext_vector_type(4))) float f32x4;
typedef __attribute__((address_space(3))) unsigned lds_u32;
typedef const __attribute__((address_space(1))) unsigned g_u32;

#define SB0() __builtin_amdgcn_sched_barrier(0)

static __device__ __forceinline__ unsigned short f2bf(float f) {
    union { float f; unsigned u; } v; v.f = f;
    unsigned r = (v.u + 0x7fffu + ((v.u >> 16) & 1u)) >> 16;  // RNE
    return (unsigned short)r;
}

static __device__ __forceinline__ unsigned pk2(float x, float y) {
    union { __hip_bfloat162 h; unsigned u; } c;
    c.h = __float22bfloat162_rn(make_float2(x, y));  // v_cvt_pk_bf16_f32
    return c.u;
}

static __device__ __forceinline__ float fast_tanh(float x) {
    return 1.0f - 2.0f / (__expf(2.0f * x) + 1.0f);
}

// ---------------- prep: sW[b,h] = sum_d s[b,d] * W_attn[h, d] ----------------
__global__ __launch_bounds__(256) void prep_sw(const float* __restrict__ s,
                                               const float* __restrict__ Wat,
                                               float* __restrict__ sW) {
    int id = blockIdx.x * 256 + threadIdx.x;   // 16384 = 32b * 512h
    int b = id >> 9, h = id & 511;
    const float4* wr = (const float4*)(Wat + (size_t)h * 1536);
    const float4* sr = (const float4*)(s + (size_t)b * 512);
    float acc = 0.f;
#pragma unroll 8
    for (int i = 0; i < 128; ++i) {
        float4 w = wr[i], sv = sr[i];
        acc += w.x * sv.x + w.y * sv.y + w.z * sv.z + w.w * sv.w;
    }
    sW[id] = acc;
}

// ------- prep: WebfB fragment-major bf16 repack of W_e = W_attn[:,512:] -----
// Layout: [cg(4)][step(32)][nf(8)][lane(64)][j(8)]
// element = W_e[col = cg*128+nf*16+(lane&15)][k = step*32+(lane>>4)*8+j]
__global__ __launch_bounds__(256) void prep_weB(const float* __restrict__ Wat,
                                                unsigned short* __restrict__ WebfB) {
    int tid = blockIdx.x * 256 + threadIdx.x;  // 0..65535
    int lane = tid & 63;
    int g = tid >> 6;
    int nf = g & 7, step = (g >> 3) & 31, cg = g >> 8;
    int col = cg * 128 + nf * 16 + (lane & 15);
    int k0 = step * 32 + (lane >> 4) * 8;
    const float* src = Wat + (size_t)col * 1536 + 512 + k0;
    float4 w0 = *(const float4*)src;
    float4 w1 = *(const float4*)(src + 4);
    union { unsigned short us[8]; int4 v; } p;
    p.us[0] = f2bf(w0.x); p.us[1] = f2bf(w0.y); p.us[2] = f2bf(w0.z); p.us[3] = f2bf(w0.w);
    p.us[4] = f2bf(w1.x); p.us[5] = f2bf(w1.y); p.us[6] = f2bf(w1.z); p.us[7] = f2bf(w1.w);
    *(int4*)(WebfB + (size_t)tid * 8) = p.v;
}

// zero atten (atomicAdd target; re-zeroed every launch -> deterministic)
__global__ __launch_bounds__(256) void zero_atten(float* __restrict__ atten) {
    atten[blockIdx.x * 256 + threadIdx.x] = 0.f;
}

// ---------------- energy+atten: atten[m] = sum_h tanh(sW+enc.W_e^T)*Wv[h] ----
// Block: 128 rows x 256 cols; 4 waves = 2 rowgroups x 2 colgroups; wave 64x128.
// K-step 32, 3 LDS A-buffers (f32, XOR-swizzled), counted-vmcnt pipeline:
// per step [wait vmcnt(12); s_barrier; loadB(i+1); stageA(i+2); compute(i)].
// Grid 1024: col-half pair (bid, bid+8) -> same XCD, 8 dispatch slots apart.
__global__ __launch_bounds__(256, 2) void energy_kernel(
    const float* __restrict__ enc, const unsigned short* __restrict__ WebfB,
    const float* __restrict__ sW, const float* __restrict__ Wv,
    float* __restrict__ atten) {
    __shared__ __align__(16) float lA[3][4096];  // 3 x 16 KiB (128 rows x 32 k)
    __shared__ float lred[4][64];

    const int t = threadIdx.x;       // 0..255
    const int lane = t & 63;
    const int wave = t >> 6;
    const int rg = wave >> 1;        // row group 0..1
    const int cgw = wave & 1;        // col group in block 0..1
    const int bid = blockIdx.x;
    const int rt = ((bid >> 4) << 3) | (bid & 7);   // 0..511
    const int ch = (bid >> 3) & 1;                  // col half
    const int m0 = rt * 128;
    const int b = m0 >> 11;
    const int l15 = lane & 15;
    const int lkg = lane >> 4;       // k-group 0..3
    const int cgAll = ch * 2 + cgw;  // 128-col group 0..3
    const int colbase = cgAll * 128;

    // A staging: 4 gload_lds/thread/step; slot s = q*256+t covers LDS 16B slot
    // (row_s = s>>3, chunk_s = s&7); content = A[row_s][k0 + (chunk_s^(row_s&7))*4]
    const float* gsrc[4];
    int ldoff[4];
#pragma unroll
    for (int q = 0; q < 4; ++q) {
        int s = q * 256 + t;
        int row_s = s >> 3;
        int chs = (s & 7) ^ (row_s & 7);
        gsrc[q] = enc + (size_t)(m0 + row_s) * 1024 + chs * 4;
        ldoff[q] = (q * 256 + wave * 64) * 4;     // wave-uniform f32 base
    }

    const unsigned short* wB = WebfB + (size_t)cgAll * 131072 + lane * 8;

    f32x4 acc[4][8];
#pragma unroll
    for (int mf = 0; mf < 4; ++mf)
#pragma unroll
        for (int nf = 0; nf < 8; ++nf) acc[mf][nf] = (f32x4){0.f, 0.f, 0.f, 0.f};

    auto stage = [&](int step, float* buf) {
#pragma unroll
        for (int q = 0; q < 4; ++q)
            __builtin_amdgcn_global_load_lds((g_u32*)(gsrc[q] + step * 32),
                                             (lds_u32*)(buf + ldoff[q]), 16, 0, 0);
    };
    auto loadB = [&](int step, bf16x8* bf) {
#pragma unroll
        for (int nf = 0; nf < 8; ++nf)
            bf[nf] = *(const bf16x8*)(wB + (((size_t)step * 8 + nf) << 9));
    };
    auto compute = [&](const float* lbuf, const bf16x8* bf) {
#pragma unroll
        for (int mf = 0; mf < 4; ++mf) {
            const int r = rg * 64 + mf * 16 + l15;    // local row 0..127
            const int r7 = r & 7;
            const int c0 = lkg * 2;
            float4 a0 = *(const float4*)&lbuf[r * 32 + ((c0 ^ r7) << 2)];
            float4 a1 = *(const float4*)&lbuf[r * 32 + (((c0 + 1) ^ r7) << 2)];
            union { unsigned u[4]; bf16x8 v; } af;
            af.u[0] = pk2(a0.x, a0.y); af.u[1] = pk2(a0.z, a0.w);
            af.u[2] = pk2(a1.x, a1.y); af.u[3] = pk2(a1.z, a1.w);
#pragma unroll
            for (int nf = 0; nf < 8; ++nf)
                acc[mf][nf] = __builtin_amdgcn_mfma_f32_16x16x32_bf16(
                    af.v, bf[nf], acc[mf][nf], 0, 0, 0);
        }
    };

    float* p0 = (float*)lA[0];
    float* p1 = (float*)lA[1];
    float* p2 = (float*)lA[2];
    bf16x8 bA[8], bB[8];

    // prologue: A(0), B(0), A(1) -> 16 vmem in flight
    stage(0, p0);
    loadB(0, bA);
    stage(1, p1);

#pragma unroll 1
    for (int k = 0; k < 15; ++k) {
        const int i = 2 * k;
        // even step i (uses bA)
        asm volatile("s_waitcnt vmcnt(12)" ::: "memory");  // A(i) in LDS
        SB0();
        __builtin_amdgcn_s_barrier();
        loadB(i + 1, bB);                                  // B before younger A
        SB0();
        stage(i + 2, p2);
        SB0();
        compute(p0, bA);
        { float* tp = p0; p0 = p1; p1 = p2; p2 = tp; }
        // odd step i+1 (uses bB)
        asm volatile("s_waitcnt vmcnt(12)" ::: "memory");
        SB0();
        __builtin_amdgcn_s_barrier();
        loadB(i + 2, bA);
        SB0();
        stage(i + 3, p2);
        SB0();
        compute(p0, bB);
        { float* tp = p0; p0 = p1; p1 = p2; p2 = tp; }
    }
    // step 30 (uses bA): no more staging
    asm volatile("s_waitcnt vmcnt(12)" ::: "memory");
    SB0();
    __builtin_amdgcn_s_barrier();
    loadB(31, bB);
    SB0();
    compute(p0, bA);
    { float* tp = p0; p0 = p1; p1 = p2; p2 = tp; }
    // step 31 (uses bB): in flight = A(31)[4] + B(31)[8]; retire A(31)
    asm volatile("s_waitcnt vmcnt(8)" ::: "memory");
    SB0();
    __builtin_amdgcn_s_barrier();
    compute(p0, bB);

    // epilogue: tanh + dot Wv over this wave's 128 cols
    float sWv[8], wvv[8];
#pragma unroll
    for (int nf = 0; nf < 8; ++nf) {
        int col = colbase + nf * 16 + l15;
        sWv[nf] = sW[(b << 9) + col];
        wvv[nf] = Wv[col];
    }
    float pa[4][4];
#pragma unroll
    for (int mf = 0; mf < 4; ++mf) {
#pragma unroll
        for (int r = 0; r < 4; ++r) pa[mf][r] = 0.f;
#pragma unroll
        for (int nf = 0; nf < 8; ++nf)
#pragma unroll
            for (int r = 0; r < 4; ++r)
                pa[mf][r] += fast_tanh(acc[mf][nf][r] + sWv[nf]) * wvv[nf];
    }
#pragma unroll
    for (int m = 1; m < 16; m <<= 1)
#pragma unroll
        for (int mf = 0; mf < 4; ++mf)
#pragma unroll
            for (int r = 0; r < 4; ++r)
                pa[mf][r] += __shfl_xor(pa[mf][r], m, 64);

    if (l15 == 0) {
#pragma unroll
        for (int mf = 0; mf < 4; ++mf)
#pragma unroll
            for (int r = 0; r < 4; ++r)
                lred[wave][mf * 16 + lkg * 4 + r] = pa[mf][r];   // wave-local row
    }
    __syncthreads();
    if (t < 128) {
        int rgw = t >> 6, lsub = t & 63;
        float ssum = lred[rgw * 2 + 0][lsub] + lred[rgw * 2 + 1][lsub];
        atomicAdd(&atten[m0 + t], ssum);   // exactly 2 contributors: deterministic
    }
}

// ---------------- softmax over S=2048 per batch row ----------------
__global__ __launch_bounds__(256) void softmax_kernel(const float* __restrict__ atten,
                                                      float* __restrict__ out) {
    int b = blockIdx.x, t = threadIdx.x;
    const float* row = atten + b * 2048;
    float v[8];
#pragma unroll
    for (int i = 0; i < 8; ++i) v[i] = row[t + 256 * i];
    float mx = v[0];
#pragma unroll
    for (int i = 1; i < 8; ++i) mx = fmaxf(mx, v[i]);
#pragma unroll
    for (int m = 1; m < 64; m <<= 1) mx = fmaxf(mx, __shfl_xor(mx, m, 64));
    __shared__ float redm[4], reds[4];
    if ((t & 63) == 0) redm[t >> 6] = mx;
    __syncthreads();
    mx = fmaxf(fmaxf(redm[0], redm[1]), fmaxf(redm[2], redm[3]));
    float sum = 0.f;
#pragma unroll
    for (int i = 0; i < 8; ++i) { v[i] = __expf(v[i] - mx); sum += v[i]; }
#pragma unroll
    for (int m = 1; m < 64; m <<= 1) sum += __shfl_xor(sum, m, 64);
    if ((t & 63) == 0) reds[t >> 6] = sum;
    __syncthreads();
    sum = reds[0] + reds[1] + reds[2] + reds[3];
    float inv = 1.0f / sum;
    float* soft = out + 32768;
#pragma unroll
    for (int i = 0; i < 8; ++i) soft[b * 2048 + t + 256 * i] = v[i] * inv;
}

// ---------------- context partial: 32 chunks of 64 rows per batch ----------
__global__ __launch_bounds__(256) void ctx_partial(const float* __restrict__ enc,
                                                   const float* __restrict__ soft,
                                                   float* __restrict__ part) {
    int blk = blockIdx.x;               // b*32 + chunk
    int b = blk >> 5, s0 = (blk & 31) * 64;
    int t = threadIdx.x;
    float4 a = {0.f, 0.f, 0.f, 0.f};
    const float* base = enc + ((size_t)(b * 2048 + s0)) * 1024 + t * 4;
    const float* sw = soft + b * 2048 + s0;
#pragma unroll 4
    for (int s = 0; s < 64; ++s) {
        float w = sw[s];
        float4 e = *(const float4*)(base + (size_t)s * 1024);
        a.x += w * e.x; a.y += w * e.y; a.z += w * e.z; a.w += w * e.w;
    }
    *(float4*)(part + (size_t)blk * 1024 + t * 4) = a;
}

__global__ __launch_bounds__(256) void ctx_reduce(const float* __restrict__ part,
                                                  float* __restrict__ ctx) {
    int id = blockIdx.x * 256 + threadIdx.x;  // 32768 = 32b * 1024e
    int b = id >> 10, e = id & 1023;
    float s = 0.f;
#pragma unroll 8
    for (int c = 0; c < 32; ++c) s += part[((size_t)(b * 32 + c)) * 1024 + e];
    ctx[id] = s;
}

extern "C" void kernel_launch(void* const* d_in, const int* in_sizes, int n_in,
                              void* d_out, int out_size, void* d_ws, size_t ws_size,
                              hipStream_t stream) {
    const float* s   = (const float*)d_in[0];
    const float* enc = (const float*)d_in[1];
    const float* Wat = (const float*)d_in[2];
    const float* Wv  = (const float*)d_in[3];
    float* out = (float*)d_out;

    char* ws = (char*)d_ws;
    float* sW             = (float*)ws;                                   // 64 KiB
    unsigned short* WebfB = (unsigned short*)(ws + (64 << 10));           // 1 MiB
    float* atten          = (float*)(ws + (64 << 10) + (1 << 20));        // 256 KiB
    float* part           = (float*)(ws + (64 << 10) + (1 << 20) + (256 << 10)); // 4 MiB

    prep_sw<<<64, 256, 0, stream>>>(s, Wat, sW);
    prep_weB<<<256, 256, 0, stream>>>(Wat, WebfB);
    zero_atten<<<256, 256, 0, stream>>>(atten);
    energy_kernel<<<1024, 256, 0, stream>>>(enc, WebfB, sW, Wv, atten);
    softmax_kernel<<<32, 256, 0, stream>>>(atten, out);
    ctx_partial<<<1024, 256, 0, stream>>>(enc, out + 32768, part);
    ctx_reduce<<<128, 256, 0, stream>>>(part, out);
}

// Round 6
// 178.106 us; speedup vs baseline: 1.0999x; 1.0119x over previous
//
#include <hip/hip_runtime.h>
#include <hip/hip_bf16.h>

// Attention head: context/softmax over (B=32, S=2048, DEC=512, ENC2=1024)
// d_in[0] = s (1,32,512) f32 | d_in[1] = enc (32,2048,1024) f32
// d_in[2] = W_attn (512,1536) f32 | d_in[3] = W_v (1,512) f32
// d_out = context (32,1024) f32 ++ soft (32,2048) f32

typedef __attribute__((ext_vector_type(8))) short bf16x8;
typedef __attribute__((ext_vector_type(4))) float f32x4;

#define SB0() __builtin_amdgcn_sched_barrier(0)

static __device__ __forceinline__ unsigned short f2bf(float f) {
    union { float f; unsigned u; } v; v.f = f;
    unsigned r = (v.u + 0x7fffu + ((v.u >> 16) & 1u)) >> 16;  // RNE
    return (unsigned short)r;
}

static __device__ __forceinline__ unsigned pk2(float x, float y) {
    union { __hip_bfloat162 h; unsigned u; } c;
    c.h = __float22bfloat162_rn(make_float2(x, y));  // v_cvt_pk_bf16_f32
    return c.u;
}

static __device__ __forceinline__ float fast_tanh(float x) {
    return 1.0f - 2.0f / (__expf(2.0f * x) + 1.0f);
}

// ---------------- prep: sW[b,h] = sum_d s[b,d] * W_attn[h, d] ----------------
__global__ __launch_bounds__(256) void prep_sw(const float* __restrict__ s,
                                               const float* __restrict__ Wat,
                                               float* __restrict__ sW) {
    int id = blockIdx.x * 256 + threadIdx.x;   // 16384 = 32b * 512h
    int b = id >> 9, h = id & 511;
    const float4* wr = (const float4*)(Wat + (size_t)h * 1536);
    const float4* sr = (const float4*)(s + (size_t)b * 512);
    float acc = 0.f;
#pragma unroll 8
    for (int i = 0; i < 128; ++i) {
        float4 w = wr[i], sv = sr[i];
        acc += w.x * sv.x + w.y * sv.y + w.z * sv.z + w.w * sv.w;
    }
    sW[id] = acc;
}

// ------- prep: WebfB fragment-major bf16 repack of W_e = W_attn[:,512:] -----
// Layout: [cg(4)][step32(32)][nf'(8)][lane(64)][j(8)]
// element = W_e[col = cg*128+nf'*16+(lane&15)][k = step32*32+(lane>>4)*8+j]
__global__ __launch_bounds__(256) void prep_weB(const float* __restrict__ Wat,
                                                unsigned short* __restrict__ WebfB) {
    int tid = blockIdx.x * 256 + threadIdx.x;  // 0..65535
    int lane = tid & 63;
    int g = tid >> 6;
    int nf = g & 7, step = (g >> 3) & 31, cg = g >> 8;
    int col = cg * 128 + nf * 16 + (lane & 15);
    int k0 = step * 32 + (lane >> 4) * 8;
    const float* src = Wat + (size_t)col * 1536 + 512 + k0;
    float4 w0 = *(const float4*)src;
    float4 w1 = *(const float4*)(src + 4);
    union { unsigned short us[8]; int4 v; } p;
    p.us[0] = f2bf(w0.x); p.us[1] = f2bf(w0.y); p.us[2] = f2bf(w0.z); p.us[3] = f2bf(w0.w);
    p.us[4] = f2bf(w1.x); p.us[5] = f2bf(w1.y); p.us[6] = f2bf(w1.z); p.us[7] = f2bf(w1.w);
    *(int4*)(WebfB + (size_t)tid * 8) = p.v;
}

// ---------------- energy: attpart[ct][m] = sum_{128 cols of ct} tanh(..)*Wv --
// Block 128r x 128c; 4 waves (rg,cgw) each 64r x 64c. Grid 2048.
// K-step 64, 16 steps; 2 bf16 LDS buffers; ONE raw barrier per step.
// A: reg-staged (global->VGPR->cvt->swizzled bf16 ds_write). B: L2-resident
// fragment-major, issued BEFORE the A(i+2) HBM loads (no transitive waits).
// bid mapping: 4 col-tiles of one row-tile land on the SAME XCD (bids +8).
__global__ __launch_bounds__(256, 3) void energy_kernel(
    const float* __restrict__ enc, const unsigned short* __restrict__ WebfB,
    const float* __restrict__ sW, const float* __restrict__ Wv,
    float* __restrict__ attpart) {
    __shared__ __align__(16) unsigned short lA[2][8192];  // 2 x 16 KiB (128r x 64k bf16)
    __shared__ float lred[4][64];

    const int t = threadIdx.x;       // 0..255
    const int lane = t & 63;
    const int wave = t >> 6;
    const int rg = wave >> 1;        // row group 0..1
    const int cgw = wave & 1;        // col group 0..1
    const int bid = blockIdx.x;
    const int ct = (bid >> 3) & 3;                    // col tile 0..3
    const int rt = ((bid >> 5) << 3) | (bid & 7);     // row tile 0..511
    const int m0 = rt * 128;
    const int b = m0 >> 11;
    const int l15 = lane & 15;
    const int lkg = lane >> 4;       // k-group 0..3

    // A staging addresses: slot s=q*256+t -> row=q*16+(t>>4), f32chunk c=t&15
    const float* abase = enc + (size_t)m0 * 1024 + (t >> 4) * 1024 + (t & 15) * 4;
    // LDS write: byte = row*128 + (c*8 ^ ((row&7)<<4)); row&7 == (t>>4)&7
    const int wlo = (t >> 4) * 128 + (((t & 15) * 8) ^ (((t >> 4) & 7) << 4));
    // LDS read: row = rg*64+mf*16+l15; chunk c4 = (kk*4+lkg)^(l15&7)
    const int rbase0 = (rg * 64 + l15) * 128 + ((lkg ^ (l15 & 7)) << 4);
    const int rbase1 = rbase0 ^ 64;   // kk=1 toggles c4 bit2

    const unsigned short* wB = WebfB + (size_t)ct * 131072 + lane * 8;

    f32x4 acc[4][4];
#pragma unroll
    for (int mf = 0; mf < 4; ++mf)
#pragma unroll
        for (int nf = 0; nf < 4; ++nf) acc[mf][nf] = (f32x4){0.f, 0.f, 0.f, 0.f};

    float4 areg[8];
    auto load8 = [&](int step) {
#pragma unroll
        for (int q = 0; q < 8; ++q)
            areg[q] = *(const float4*)(abase + q * 16384 + step * 64);
    };
    auto cvtwrite = [&](unsigned short* buf) {
        char* base = (char*)buf + wlo;
#pragma unroll
        for (int q = 0; q < 8; ++q) {
            uint2 w;
            w.x = pk2(areg[q].x, areg[q].y);
            w.y = pk2(areg[q].z, areg[q].w);
            *(uint2*)(base + q * 2048) = w;
        }
    };
    bf16x8 bfr[8];
    auto loadB = [&](int i) {
#pragma unroll
        for (int kk = 0; kk < 2; ++kk)
#pragma unroll
            for (int nf = 0; nf < 4; ++nf)
                bfr[kk * 4 + nf] = *(const bf16x8*)(
                    wB + (((size_t)((i * 2 + kk) * 8 + cgw * 4 + nf)) << 9));
    };
    auto compute = [&](const unsigned short* buf) {
#pragma unroll
        for (int kk = 0; kk < 2; ++kk) {
            const int rb = kk ? rbase1 : rbase0;
#pragma unroll
            for (int mf = 0; mf < 4; ++mf) {
                bf16x8 af = *(const bf16x8*)((const char*)buf + rb + mf * 2048);
#pragma unroll
                for (int nf = 0; nf < 4; ++nf)
                    acc[mf][nf] = __builtin_amdgcn_mfma_f32_16x16x32_bf16(
                        af, bfr[kk * 4 + nf], acc[mf][nf], 0, 0, 0);
            }
        }
    };

    unsigned short* cur = lA[0];
    unsigned short* nxt = lA[1];

    // prologue: A(0) -> buf0; A(1) in flight
    load8(0);
    cvtwrite(cur);          // auto-waits A(0) regs
    load8(1);
    asm volatile("s_waitcnt lgkmcnt(0)" ::: "memory");
    __builtin_amdgcn_s_barrier();

#pragma unroll 2
    for (int i = 0; i < 16; ++i) {
        loadB(i);                       // L2 loads issued first
        SB0();
        if (i < 15) cvtwrite(nxt);      // waits A(i+1) regs (HBM, ~1 step cover)
        SB0();
        if (i < 14) load8(i + 2);       // HBM prefetch, newest in queue
        SB0();
        compute(cur);                   // B-wait counts only the A(i+2) loads
        asm volatile("s_waitcnt lgkmcnt(0)" ::: "memory");
        SB0();
        __builtin_amdgcn_s_barrier();
        { unsigned short* tp = cur; cur = nxt; nxt = tp; }
    }

    // epilogue: tanh + dot Wv over this wave's 64 cols
    float sWv[4], wvv[4];
#pragma unroll
    for (int nf = 0; nf < 4; ++nf) {
        int col = ct * 128 + cgw * 64 + nf * 16 + l15;
        sWv[nf] = sW[(b << 9) + col];
        wvv[nf] = Wv[col];
    }
    float pa[4][4];
#pragma unroll
    for (int mf = 0; mf < 4; ++mf) {
#pragma unroll
        for (int r = 0; r < 4; ++r) pa[mf][r] = 0.f;
#pragma unroll
        for (int nf = 0; nf < 4; ++nf)
#pragma unroll
            for (int r = 0; r < 4; ++r)
                pa[mf][r] += fast_tanh(acc[mf][nf][r] + sWv[nf]) * wvv[nf];
    }
#pragma unroll
    for (int m = 1; m < 16; m <<= 1)
#pragma unroll
        for (int mf = 0; mf < 4; ++mf)
#pragma unroll
            for (int r = 0; r < 4; ++r)
                pa[mf][r] += __shfl_xor(pa[mf][r], m, 64);

    if (l15 == 0) {
#pragma unroll
        for (int mf = 0; mf < 4; ++mf)
#pragma unroll
            for (int r = 0; r < 4; ++r)
                lred[wave][mf * 16 + lkg * 4 + r] = pa[mf][r];
    }
    __syncthreads();
    if (t < 128) {
        int rgw = t >> 6, rl = t & 63;
        attpart[(size_t)ct * 65536 + m0 + t] =
            lred[rgw * 2 + 0][rl] + lred[rgw * 2 + 1][rl];
    }
}

// ---------------- softmax over S=2048 per batch row (sums 4 col partials) ---
__global__ __launch_bounds__(256) void softmax_kernel(const float* __restrict__ attpart,
                                                      float* __restrict__ out) {
    int b = blockIdx.x, t = threadIdx.x;
    float v[8];
#pragma unroll
    for (int i = 0; i < 8; ++i) {
        int idx = b * 2048 + t + 256 * i;
        v[i] = ((attpart[idx] + attpart[65536 + idx]) + attpart[131072 + idx])
               + attpart[196608 + idx];
    }
    float mx = v[0];
#pragma unroll
    for (int i = 1; i < 8; ++i) mx = fmaxf(mx, v[i]);
#pragma unroll
    for (int m = 1; m < 64; m <<= 1) mx = fmaxf(mx, __shfl_xor(mx, m, 64));
    __shared__ float redm[4], reds[4];
    if ((t & 63) == 0) redm[t >> 6] = mx;
    __syncthreads();
    mx = fmaxf(fmaxf(redm[0], redm[1]), fmaxf(redm[2], redm[3]));
    float sum = 0.f;
#pragma unroll
    for (int i = 0; i < 8; ++i) { v[i] = __expf(v[i] - mx); sum += v[i]; }
#pragma unroll
    for (int m = 1; m < 64; m <<= 1) sum += __shfl_xor(sum, m, 64);
    if ((t & 63) == 0) reds[t >> 6] = sum;
    __syncthreads();
    sum = reds[0] + reds[1] + reds[2] + reds[3];
    float inv = 1.0f / sum;
    float* soft = out + 32768;
#pragma unroll
    for (int i = 0; i < 8; ++i) soft[b * 2048 + t + 256 * i] = v[i] * inv;
}

// ---------------- context partial: 16 chunks of 128 rows per batch ----------
__global__ __launch_bounds__(256) void ctx_partial(const float* __restrict__ enc,
                                                   const float* __restrict__ soft,
                                                   float* __restrict__ part) {
    int blk = blockIdx.x;               // b*16 + chunk
    int b = blk >> 4, s0 = (blk & 15) * 128;
    int t = threadIdx.x;
    float4 a = {0.f, 0.f, 0.f, 0.f};
    const float* base = enc + ((size_t)(b * 2048 + s0)) * 1024 + t * 4;
    const float* sw = soft + b * 2048 + s0;
#pragma unroll 4
    for (int s = 0; s < 128; ++s) {
        float w = sw[s];
        float4 e = *(const float4*)(base + (size_t)s * 1024);
        a.x += w * e.x; a.y += w * e.y; a.z += w * e.z; a.w += w * e.w;
    }
    *(float4*)(part + (size_t)blk * 1024 + t * 4) = a;
}

__global__ __launch_bounds__(256) void ctx_reduce(const float* __restrict__ part,
                                                  float* __restrict__ ctx) {
    int id = blockIdx.x * 256 + threadIdx.x;  // 32768 = 32b * 1024e
    int b = id >> 10, e = id & 1023;
    float s = 0.f;
#pragma unroll 8
    for (int c = 0; c < 16; ++c) s += part[((size_t)(b * 16 + c)) * 1024 + e];
    ctx[id] = s;
}

extern "C" void kernel_launch(void* const* d_in, const int* in_sizes, int n_in,
                              void* d_out, int out_size, void* d_ws, size_t ws_size,
                              hipStream_t stream) {
    const float* s   = (const float*)d_in[0];
    const float* enc = (const float*)d_in[1];
    const float* Wat = (const float*)d_in[2];
    const float* Wv  = (const float*)d_in[3];
    float* out = (float*)d_out;

    char* ws = (char*)d_ws;
    float* sW             = (float*)ws;                                   // 64 KiB
    unsigned short* WebfB = (unsigned short*)(ws + (64 << 10));           // 1 MiB
    float* attpart        = (float*)(ws + (64 << 10) + (1 << 20));        // 1 MiB
    float* part           = (float*)(ws + (64 << 10) + (2 << 20));        // 2 MiB

    prep_sw<<<64, 256, 0, stream>>>(s, Wat, sW);
    prep_weB<<<256, 256, 0, stream>>>(Wat, WebfB);
    energy_kernel<<<2048, 256, 0, stream>>>(enc, WebfB, sW, Wv, attpart);
    softmax_kernel<<<32, 256, 0, stream>>>(attpart, out);
    ctx_partial<<<512, 256, 0, stream>>>(enc, out + 32768, part);
    ctx_reduce<<<128, 256, 0, stream>>>(part, out);
}